// Round 1
// baseline (562.292 us; speedup 1.0000x reference)
//
#include <hip/hip_runtime.h>

// Perona-Malik diffusion, 500 iters = 50 launches x 10 LDS-fused steps.
// Round-5 change vs round 4: trapezoid (light-cone) predication inside the
// fused loop. A region quad at ring distance r from the region edge only
// matters for iterations it < r (garbage walks inward 1 ring/iter; the
// interior tile has ring >= 10 = T_FUSE so it is always live). We now skip
// read+compute+write for dead quads: ~31% of LDS lane-traffic and the
// dead-halo waves' VALU disappear, bit-identically for the interior.
// This also kills the phantom writes: threads with qi >= NQUAD used to
// write zero float4s to quad-0's LDS slot every iteration (392 redundant
// same-address b128 writes/iter + a benign prologue race) — now live=0.

#define HH 512
#define WW 512
#define NB 2
static constexpr float LAM   = 0.24f;
static constexpr float KCOND = 0.03f;
static constexpr float DEPS_ = 0.1f;
static constexpr int IMG      = HH * WW;
static constexpr int N_DEPTH  = NB * IMG;
static constexpr int CV_PER_B = (HH - 1) * WW;
static constexpr int CH_PER_B = HH * (WW - 1);
static constexpr int N_CV     = NB * CV_PER_B;
static constexpr int N_CH     = NB * CH_PER_B;

static constexpr int T_FUSE = 10, NSS = 50;       // 50 x 10 = 500
static constexpr int TILE_W = 64, TILE_H = 32;
static constexpr int HALO_X = 12, HALO_Y = 10;
static constexpr int RW = TILE_W + 2 * HALO_X;    // 88
static constexpr int RH = TILE_H + 2 * HALO_Y;    // 52
static constexpr int NQ_ROW = RW / 4;             // 22
static constexpr int NQUAD  = NQ_ROW * RH;        // 1144
static constexpr int SSZ    = (RH + 2) * RW;      // +guard rows

// fast path: 512 threads, 3 quads/thread
static constexpr int NT  = 512;
static constexpr int QPT = 3;                      // ceil(1144/512)
// coefficient planes (per block): CV rows 0..RH (edge above region row r),
// CH row width padded to 96 so the 5-edge read is aligned f4 + scalar.
static constexpr int CVW = RW;                     // 88
static constexpr int CV_SZ = (RH + 1) * CVW;       // 4664
static constexpr int CHW = RW + 8;                 // 96
static constexpr int CH_SZ = RH * CHW;             // 4992
static constexpr int BLOB_BLK = CV_SZ + CH_SZ;     // 9656 floats/block

// fallback path (round-2 verified): 256 threads, 5 quads/thread
static constexpr int QPT_F = 5;

// ---- monotone float<->uint key for atomic min ----
__device__ __forceinline__ unsigned fkey(float f) {
    unsigned u = __float_as_uint(f);
    return (u & 0x80000000u) ? ~u : (u | 0x80000000u);
}
__device__ __forceinline__ float kinv(unsigned k) {
    return __uint_as_float((k & 0x80000000u) ? (k & 0x7fffffffu) : ~k);
}

__global__ void init_key_kernel(unsigned* key) { *key = 0xFFFFFFFFu; }

__global__ void min_kernel(const float* __restrict__ x, unsigned* key) {
    float m = 3.4e38f;
    for (int idx = blockIdx.x * blockDim.x + threadIdx.x; idx < N_DEPTH;
         idx += gridDim.x * blockDim.x)
        m = fminf(m, x[idx]);
    for (int off = 32; off > 0; off >>= 1) m = fminf(m, __shfl_down(m, off, 64));
    __shared__ float sm[4];
    int lane = threadIdx.x & 63, wv = threadIdx.x >> 6;
    if (lane == 0) sm[wv] = m;
    __syncthreads();
    if (threadIdx.x == 0) {
        float mm = fminf(fminf(sm[0], sm[1]), fminf(sm[2], sm[3]));
        atomicMin(key, fkey(mm));
    }
}

__global__ void coeff_kernel(const float* __restrict__ g, float* __restrict__ cv,
                             float* __restrict__ chh) {
    int idx = blockIdx.x * blockDim.x + threadIdx.x;
    constexpr float kk = KCOND * KCOND;
    if (idx < N_CV) {
        int b = idx / CV_PER_B;
        int r = idx - b * CV_PER_B;
        int i = r >> 9, j = r & (WW - 1);
        const float* gb = g + b * 3 * IMG + i * WW + j;
        float s = 0.f;
#pragma unroll
        for (int c = 0; c < 3; ++c) s += fabsf(gb[c * IMG + WW] - gb[c * IMG]);
        float m = s / 3.0f;
        cv[idx] = 1.0f / (1.0f + (m * m) / kk);
    } else if (idx < N_CV + N_CH) {
        int t = idx - N_CV;
        int b = t / CH_PER_B;
        int r = t - b * CH_PER_B;
        int i = r / (WW - 1);
        int j = r - i * (WW - 1);
        const float* gb = g + b * 3 * IMG + i * WW + j;
        float s = 0.f;
#pragma unroll
        for (int c = 0; c < 3; ++c) s += fabsf(gb[c * IMG + 1] - gb[c * IMG]);
        float m = s / 3.0f;
        chh[t] = 1.0f / (1.0f + (m * m) / kk);
    }
}

// One-time: bake predicated L*cv / L*ch into dense per-block planes.
// CV[rr][x] = coeff of vertical edge ABOVE region row rr (0 where invalid):
//   cu(quad row r) = CV[r], cd(quad row r) = CV[r+1].
// CH[rr][xe] = coeff of horizontal edge whose RIGHT pixel is region col xe.
__global__ __launch_bounds__(256) void prep_planes(const float* __restrict__ cv_g,
                                                   const float* __restrict__ ch_g,
                                                   float* __restrict__ blob) {
    const int blk = blockIdx.x;
    const int b   = blk >> 7, t = blk & 127;
    const int y0  = (t >> 3) * TILE_H;
    const int x0  = (t & 7) * TILE_W;
    const float* cvb = cv_g + b * CV_PER_B;
    const float* chb = ch_g + b * CH_PER_B;
    float* pv = blob + blk * BLOB_BLK;
    float* ph = pv + CV_SZ;
    for (int i = threadIdx.x; i < CV_SZ; i += 256) {
        int rr = i / CVW, x = i - rr * CVW;
        int gy = y0 - HALO_Y + rr, gx = x0 - HALO_X + x;
        bool ok = (rr >= 1) && (rr <= RH - 1) && (gy >= 1) && (gy <= HH - 1) &&
                  (gx >= 0) && (gx < WW);
        pv[i] = ok ? LAM * cvb[(gy - 1) * WW + gx] : 0.f;
    }
    for (int i = threadIdx.x; i < CH_SZ; i += 256) {
        int rr = i / CHW, xe = i - rr * CHW;
        int gy = y0 - HALO_Y + rr, gxe = x0 - HALO_X + xe;
        bool ok = (xe >= 1) && (xe <= RW - 1) && (gy >= 0) && (gy < HH) &&
                  (gxe >= 1) && (gxe < WW);
        ph[i] = ok ? LAM * chb[gy * (WW - 1) + (gxe - 1)] : 0.f;
    }
}

template <bool ADD_SHIFT, bool SUB_SHIFT>
__global__ __launch_bounds__(NT, 1) void step_fast(
    const float* __restrict__ src, float* __restrict__ dst,
    const float* __restrict__ blob, const unsigned* __restrict__ key) {
    __shared__ float sb[2][SSZ];
    const int blk = blockIdx.x;
    const int b   = blk >> 7, t = blk & 127;
    const int y0  = (t >> 3) * TILE_H;
    const int x0  = (t & 7) * TILE_W;
    const float* srcb = src + b * IMG;
    const float* pv   = blob + blk * BLOB_BLK;
    const float* ph   = pv + CV_SZ;

    float shift = 0.f;
    if (ADD_SHIFT || SUB_SHIFT) shift = (kinv(*key) <= DEPS_) ? DEPS_ : 0.f;
    const int tid = threadIdx.x;

    float v[QPT][4], cu[QPT][4], cd[QPT][4], chq[QPT][5];
    int   roff[QPT], goff[QPT], live[QPT];
    bool  is_int[QPT], in_img[QPT], actq[QPT];

#pragma unroll
    for (int q = 0; q < QPT; ++q) {
        int qi   = tid + q * NT;
        bool act = qi < NQUAD;
        actq[q]  = act;
        int qc   = act ? qi : 0;
        int r    = qc / NQ_ROW;
        int x    = (qc - r * NQ_ROW) * 4;
        roff[q]  = (r + 1) * RW + x;
        // light-cone liveness: quad at ring distance `ring` from the region
        // edge is only needed for iterations it < ring. Interior ring >= 10.
        int ry   = (r < RH - 1 - r) ? r : (RH - 1 - r);
        int rx   = (x < RW - 4 - x) ? x : (RW - 4 - x);
        live[q]  = act ? ((ry < rx) ? ry : rx) : 0;
        int gy = y0 - HALO_Y + r, gx = x0 - HALO_X + x;
        bool gy_in = (gy >= 0) && (gy < HH);
        in_img[q]  = act && gy_in && (gx >= 0) && (gx <= WW - 4);
        goff[q]    = in_img[q] ? (gy * WW + gx) : 0;
        is_int[q]  = act && (r >= HALO_Y) && (r < HALO_Y + TILE_H) &&
                     (x >= HALO_X) && (x < HALO_X + TILE_W);
        float4 a  = *reinterpret_cast<const float4*>(&pv[r * CVW + x]);
        float4 d  = *reinterpret_cast<const float4*>(&pv[(r + 1) * CVW + x]);
        float4 h  = *reinterpret_cast<const float4*>(&ph[r * CHW + x]);
        float  h4 = ph[r * CHW + x + 4];
        float am = act ? 1.f : 0.f;
        cu[q][0] = a.x * am; cu[q][1] = a.y * am; cu[q][2] = a.z * am; cu[q][3] = a.w * am;
        cd[q][0] = d.x * am; cd[q][1] = d.y * am; cd[q][2] = d.z * am; cd[q][3] = d.w * am;
        chq[q][0] = h.x * am; chq[q][1] = h.y * am; chq[q][2] = h.z * am;
        chq[q][3] = h.w * am; chq[q][4] = h4 * am;
        float4 tv = {0.f, 0.f, 0.f, 0.f};
        if (in_img[q]) tv = *reinterpret_cast<const float4*>(srcb + goff[q]);
        if (ADD_SHIFT && in_img[q]) {
            tv.x += shift; tv.y += shift; tv.z += shift; tv.w += shift;
        }
        v[q][0] = tv.x; v[q][1] = tv.y; v[q][2] = tv.z; v[q][3] = tv.w;
    }

    for (int i = tid; i < RW; i += NT) {
        sb[0][i] = 0.f; sb[0][(RH + 1) * RW + i] = 0.f;
        sb[1][i] = 0.f; sb[1][(RH + 1) * RW + i] = 0.f;
    }
    // prologue store: only real quads (kills the old same-address race on
    // quad 0's slot from the qi >= NQUAD tail threads)
#pragma unroll
    for (int q = 0; q < QPT; ++q)
        if (actq[q])
            *reinterpret_cast<float4*>(&sb[0][roff[q]]) =
                float4{v[q][0], v[q][1], v[q][2], v[q][3]};
    __syncthreads();

    int cur = 0;
    for (int it = 0; it < T_FUSE; ++it) {
        float nv[QPT][4];
#pragma unroll
        for (int q = 0; q < QPT; ++q) {
            if (it < live[q]) {
                const float* s = sb[cur];
                float4 up = *reinterpret_cast<const float4*>(&s[roff[q] - RW]);
                float4 dn = *reinterpret_cast<const float4*>(&s[roff[q] + RW]);
                float  lf = s[roff[q] - 1];
                float  rt = s[roff[q] + 4];
                float c0 = v[q][0], c1 = v[q][1], c2 = v[q][2], c3 = v[q][3];
                nv[q][0] = c0 - cu[q][0] * (c0 - up.x) + cd[q][0] * (dn.x - c0)
                              - chq[q][0] * (c0 - lf) + chq[q][1] * (c1 - c0);
                nv[q][1] = c1 - cu[q][1] * (c1 - up.y) + cd[q][1] * (dn.y - c1)
                              - chq[q][1] * (c1 - c0) + chq[q][2] * (c2 - c1);
                nv[q][2] = c2 - cu[q][2] * (c2 - up.z) + cd[q][2] * (dn.z - c2)
                              - chq[q][2] * (c2 - c1) + chq[q][3] * (c3 - c2);
                nv[q][3] = c3 - cu[q][3] * (c3 - up.w) + cd[q][3] * (dn.w - c3)
                              - chq[q][3] * (c3 - c2) + chq[q][4] * (rt - c3);
            }
        }
        int nxt = cur ^ 1;
#pragma unroll
        for (int q = 0; q < QPT; ++q) {
            if (it < live[q]) {
                *reinterpret_cast<float4*>(&sb[nxt][roff[q]]) =
                    float4{nv[q][0], nv[q][1], nv[q][2], nv[q][3]};
                v[q][0] = nv[q][0]; v[q][1] = nv[q][1];
                v[q][2] = nv[q][2]; v[q][3] = nv[q][3];
            }
        }
        cur = nxt;
        __syncthreads();
    }

    float* dstb = dst + b * IMG;
#pragma unroll
    for (int q = 0; q < QPT; ++q) {
        if (is_int[q]) {
            float4 o{v[q][0], v[q][1], v[q][2], v[q][3]};
            if (SUB_SHIFT) { o.x -= shift; o.y -= shift; o.z -= shift; o.w -= shift; }
            *reinterpret_cast<float4*>(dstb + goff[q]) = o;
        }
    }
}

// -------- fallback (round-2 verified, inline gather, 256 threads) --------
template <bool ADD_SHIFT, bool SUB_SHIFT>
__global__ __launch_bounds__(256, 1) void step_fused(
    const float* __restrict__ src, float* __restrict__ dst,
    const float* __restrict__ cv_g, const float* __restrict__ ch_g,
    const unsigned* __restrict__ key) {
    __shared__ float sb[2][SSZ];
    const int blk = blockIdx.x;
    const int b = blk >> 7, t = blk & 127;
    const int y0 = (t >> 3) * TILE_H, x0 = (t & 7) * TILE_W;
    const float* cvb = cv_g + b * CV_PER_B;
    const float* chb = ch_g + b * CH_PER_B;
    const float* srcb = src + b * IMG;
    float* dstb = dst + b * IMG;
    float shift = 0.f;
    if (ADD_SHIFT || SUB_SHIFT) shift = (kinv(*key) <= DEPS_) ? DEPS_ : 0.f;
    const int tid = threadIdx.x;
    float v[QPT_F][4], cu[QPT_F][4], cd[QPT_F][4], chq[QPT_F][5];
    int roff[QPT_F], rr[QPT_F], xx[QPT_F];
    bool act[QPT_F];
#pragma unroll
    for (int q = 0; q < QPT_F; ++q) {
        int qi = tid + q * 256;
        act[q] = qi < NQUAD;
        int qc = act[q] ? qi : 0;
        int r = qc / NQ_ROW;
        int x = (qc - r * NQ_ROW) * 4;
        rr[q] = r; xx[q] = x;
        roff[q] = (r + 1) * RW + x;
        int gy = y0 - HALO_Y + r, gx = x0 - HALO_X + x;
        bool gy_in = (gy >= 0) && (gy < HH);
#pragma unroll
        for (int j = 0; j < 4; ++j) {
            int gxx = gx + j;
            bool gx_in = (gxx >= 0) && (gxx < WW);
            bool vin = act[q] && gy_in && gx_in;
            float val = vin ? srcb[gy * WW + gxx] : 0.f;
            if (ADD_SHIFT) val += shift;
            v[q][j] = vin ? val : 0.f;
            bool up_ok = act[q] && (r >= 1) && (gy >= 1) && (gy < HH) && gx_in;
            cu[q][j] = up_ok ? LAM * cvb[(gy - 1) * WW + gxx] : 0.f;
            bool dn_ok = act[q] && (r <= RH - 2) && (gy >= 0) && (gy < HH - 1) && gx_in;
            cd[q][j] = dn_ok ? LAM * cvb[gy * WW + gxx] : 0.f;
        }
#pragma unroll
        for (int jj = 0; jj < 5; ++jj) {
            int xe = x + jj, gxe = gx + jj;
            bool ok = act[q] && (xe >= 1) && (xe <= RW - 1) && gy_in &&
                      (gxe >= 1) && (gxe < WW);
            chq[q][jj] = ok ? LAM * chb[gy * (WW - 1) + (gxe - 1)] : 0.f;
        }
    }
    for (int i = tid; i < RW; i += 256) {
        sb[0][i] = 0.f; sb[0][(RH + 1) * RW + i] = 0.f;
        sb[1][i] = 0.f; sb[1][(RH + 1) * RW + i] = 0.f;
    }
#pragma unroll
    for (int q = 0; q < QPT_F; ++q)
        if (act[q])
            *reinterpret_cast<float4*>(&sb[0][roff[q]]) =
                float4{v[q][0], v[q][1], v[q][2], v[q][3]};
    __syncthreads();
    int cur = 0;
    for (int it = 0; it < T_FUSE; ++it) {
        float nv[QPT_F][4];
#pragma unroll
        for (int q = 0; q < QPT_F; ++q) {
            const float* s = sb[cur];
            float4 up = *reinterpret_cast<const float4*>(&s[roff[q] - RW]);
            float4 dn = *reinterpret_cast<const float4*>(&s[roff[q] + RW]);
            float lf = s[roff[q] - 1];
            float rt = s[roff[q] + 4];
            float c0 = v[q][0], c1 = v[q][1], c2 = v[q][2], c3 = v[q][3];
            nv[q][0] = c0 - cu[q][0] * (c0 - up.x) + cd[q][0] * (dn.x - c0)
                          - chq[q][0] * (c0 - lf) + chq[q][1] * (c1 - c0);
            nv[q][1] = c1 - cu[q][1] * (c1 - up.y) + cd[q][1] * (dn.y - c1)
                          - chq[q][1] * (c1 - c0) + chq[q][2] * (c2 - c1);
            nv[q][2] = c2 - cu[q][2] * (c2 - up.z) + cd[q][2] * (dn.z - c2)
                          - chq[q][2] * (c2 - c1) + chq[q][3] * (c3 - c2);
            nv[q][3] = c3 - cu[q][3] * (c3 - up.w) + cd[q][3] * (dn.w - c3)
                          - chq[q][3] * (c3 - c2) + chq[q][4] * (rt - c3);
        }
        int nxt = cur ^ 1;
#pragma unroll
        for (int q = 0; q < QPT_F; ++q) {
            if (act[q])
                *reinterpret_cast<float4*>(&sb[nxt][roff[q]]) =
                    float4{nv[q][0], nv[q][1], nv[q][2], nv[q][3]};
            v[q][0] = nv[q][0]; v[q][1] = nv[q][1];
            v[q][2] = nv[q][2]; v[q][3] = nv[q][3];
        }
        cur = nxt;
        __syncthreads();
    }
#pragma unroll
    for (int q = 0; q < QPT_F; ++q) {
        if (!act[q]) continue;
        int r = rr[q], x = xx[q];
        if (r >= HALO_Y && r < HALO_Y + TILE_H && x >= HALO_X && x < HALO_X + TILE_W) {
            int gy = y0 - HALO_Y + r, gx = x0 - HALO_X + x;
            float4 o{v[q][0], v[q][1], v[q][2], v[q][3]};
            if (SUB_SHIFT) { o.x -= shift; o.y -= shift; o.z -= shift; o.w -= shift; }
            *reinterpret_cast<float4*>(dstb + gy * WW + gx) = o;
        }
    }
}

extern "C" void kernel_launch(void* const* d_in, const int* in_sizes, int n_in,
                              void* d_out, int out_size, void* d_ws, size_t ws_size,
                              hipStream_t stream) {
    const float* guide   = (const float*)d_in[0];
    const float* initial = (const float*)d_in[1];
    float* out    = (float*)d_out;
    float* out_y  = out;
    float* out_cv = out + N_DEPTH;
    float* out_ch = out + N_DEPTH + N_CV;

    unsigned* key = (unsigned*)d_ws;
    float* wsf    = (float*)d_ws;
    float* bufA   = wsf + 64;
    float* bufB   = bufA + N_DEPTH;
    float* blob   = bufB + N_DEPTH;

    const size_t need = (size_t)(64 + 2 * N_DEPTH + 256 * BLOB_BLK) * 4;
    const bool fast = ws_size >= need;

    hipLaunchKernelGGL(init_key_kernel, dim3(1), dim3(1), 0, stream, key);
    hipLaunchKernelGGL(min_kernel, dim3(256), dim3(256), 0, stream, initial, key);

    int nco = N_CV + N_CH;
    hipLaunchKernelGGL(coeff_kernel, dim3((nco + 255) / 256), dim3(256), 0, stream,
                       guide, out_cv, out_ch);
    if (fast)
        hipLaunchKernelGGL(prep_planes, dim3(256), dim3(256), 0, stream,
                           out_cv, out_ch, blob);

    float* bufs[2] = {bufA, bufB};
    for (int k = 0; k < NSS; ++k) {
        const float* src = (k == 0) ? initial : bufs[(k + 1) & 1];
        float*       dst = (k == NSS - 1) ? out_y : bufs[k & 1];
        if (fast) {
            if (k == 0)
                hipLaunchKernelGGL((step_fast<true, false>), dim3(256), dim3(NT), 0,
                                   stream, src, dst, blob, key);
            else if (k == NSS - 1)
                hipLaunchKernelGGL((step_fast<false, true>), dim3(256), dim3(NT), 0,
                                   stream, src, dst, blob, key);
            else
                hipLaunchKernelGGL((step_fast<false, false>), dim3(256), dim3(NT), 0,
                                   stream, src, dst, blob, key);
        } else {
            if (k == 0)
                hipLaunchKernelGGL((step_fused<true, false>), dim3(256), dim3(256), 0,
                                   stream, src, dst, out_cv, out_ch, key);
            else if (k == NSS - 1)
                hipLaunchKernelGGL((step_fused<false, true>), dim3(256), dim3(256), 0,
                                   stream, src, dst, out_cv, out_ch, key);
            else
                hipLaunchKernelGGL((step_fused<false, false>), dim3(256), dim3(256), 0,
                                   stream, src, dst, out_cv, out_ch, key);
        }
    }
}

// Round 2
// 498.375 us; speedup vs baseline: 1.1283x; 1.1283x over previous
//
#include <hip/hip_runtime.h>

// Perona-Malik diffusion, 500 iters = 50 launches x 10 LDS-fused steps.
// Round-6 change vs round 4 (round-5 predication REVERTED: per-quad branches
// broke straight-line DS issue and quad-granular light-cones leaked stale
// values horizontally): thread ownership regrouped from 3 scattered quads
// (4x1) per thread to ONE 4-wide x 2-tall unit per thread (576 threads,
// 572 units). The vertical edge between the unit's two rows lives in
// registers, so per unit-iter the LDS traffic is:
//   1 b128 up-read + 1 b128 dn-read + 4 b32 lf/rt + 2 b128 writes
// = 4 b128 per 2 quads (was 6) with zero masked-slack (was 25%).
// Masked lanes (4 of 576) write to a trash row -- no branches in the loop.
// Per-cell arithmetic keeps the exact association order -> bit-identical.

#define HH 512
#define WW 512
#define NB 2
static constexpr float LAM   = 0.24f;
static constexpr float KCOND = 0.03f;
static constexpr float DEPS_ = 0.1f;
static constexpr int IMG      = HH * WW;
static constexpr int N_DEPTH  = NB * IMG;
static constexpr int CV_PER_B = (HH - 1) * WW;
static constexpr int CH_PER_B = HH * (WW - 1);
static constexpr int N_CV     = NB * CV_PER_B;
static constexpr int N_CH     = NB * CH_PER_B;

static constexpr int T_FUSE = 10, NSS = 50;       // 50 x 10 = 500
static constexpr int TILE_W = 64, TILE_H = 32;
static constexpr int HALO_X = 12, HALO_Y = 10;
static constexpr int RW = TILE_W + 2 * HALO_X;    // 88
static constexpr int RH = TILE_H + 2 * HALO_Y;    // 52
static constexpr int NQ_ROW = RW / 4;             // 22
static constexpr int NQUAD  = NQ_ROW * RH;        // 1144
static constexpr int SSZ    = (RH + 2) * RW;      // +guard rows (4752)

// fast path: 4x2 units, one per thread
static constexpr int NU_ROW = RW / 4;              // 22 units per row-pair
static constexpr int NU_COL = RH / 2;              // 26 row-pairs
static constexpr int NUNIT  = NU_ROW * NU_COL;     // 572
static constexpr int NTF    = 576;                 // 9 waves
static constexpr int SB_TOT = SSZ + 3 * RW;        // + trash rows

// coefficient planes (per block): CV rows 0..RH (edge above region row r),
// CH row width padded to 96 so the 5-edge read is aligned f4 + scalar.
static constexpr int CVW = RW;                     // 88
static constexpr int CV_SZ = (RH + 1) * CVW;       // 4664
static constexpr int CHW = RW + 8;                 // 96
static constexpr int CH_SZ = RH * CHW;             // 4992
static constexpr int BLOB_BLK = CV_SZ + CH_SZ;     // 9656 floats/block

// fallback path (round-2 verified): 256 threads, 5 quads/thread
static constexpr int QPT_F = 5;

// ---- monotone float<->uint key for atomic min ----
__device__ __forceinline__ unsigned fkey(float f) {
    unsigned u = __float_as_uint(f);
    return (u & 0x80000000u) ? ~u : (u | 0x80000000u);
}
__device__ __forceinline__ float kinv(unsigned k) {
    return __uint_as_float((k & 0x80000000u) ? (k & 0x7fffffffu) : ~k);
}

__global__ void init_key_kernel(unsigned* key) { *key = 0xFFFFFFFFu; }

__global__ void min_kernel(const float* __restrict__ x, unsigned* key) {
    float m = 3.4e38f;
    for (int idx = blockIdx.x * blockDim.x + threadIdx.x; idx < N_DEPTH;
         idx += gridDim.x * blockDim.x)
        m = fminf(m, x[idx]);
    for (int off = 32; off > 0; off >>= 1) m = fminf(m, __shfl_down(m, off, 64));
    __shared__ float sm[4];
    int lane = threadIdx.x & 63, wv = threadIdx.x >> 6;
    if (lane == 0) sm[wv] = m;
    __syncthreads();
    if (threadIdx.x == 0) {
        float mm = fminf(fminf(sm[0], sm[1]), fminf(sm[2], sm[3]));
        atomicMin(key, fkey(mm));
    }
}

__global__ void coeff_kernel(const float* __restrict__ g, float* __restrict__ cv,
                             float* __restrict__ chh) {
    int idx = blockIdx.x * blockDim.x + threadIdx.x;
    constexpr float kk = KCOND * KCOND;
    if (idx < N_CV) {
        int b = idx / CV_PER_B;
        int r = idx - b * CV_PER_B;
        int i = r >> 9, j = r & (WW - 1);
        const float* gb = g + b * 3 * IMG + i * WW + j;
        float s = 0.f;
#pragma unroll
        for (int c = 0; c < 3; ++c) s += fabsf(gb[c * IMG + WW] - gb[c * IMG]);
        float m = s / 3.0f;
        cv[idx] = 1.0f / (1.0f + (m * m) / kk);
    } else if (idx < N_CV + N_CH) {
        int t = idx - N_CV;
        int b = t / CH_PER_B;
        int r = t - b * CH_PER_B;
        int i = r / (WW - 1);
        int j = r - i * (WW - 1);
        const float* gb = g + b * 3 * IMG + i * WW + j;
        float s = 0.f;
#pragma unroll
        for (int c = 0; c < 3; ++c) s += fabsf(gb[c * IMG + 1] - gb[c * IMG]);
        float m = s / 3.0f;
        chh[t] = 1.0f / (1.0f + (m * m) / kk);
    }
}

// One-time: bake predicated L*cv / L*ch into dense per-block planes.
// CV[rr][x] = coeff of vertical edge ABOVE region row rr (0 where invalid):
//   cu(region row r) = CV[r], cd(region row r) = CV[r+1].
// CH[rr][xe] = coeff of horizontal edge whose RIGHT pixel is region col xe.
__global__ __launch_bounds__(256) void prep_planes(const float* __restrict__ cv_g,
                                                   const float* __restrict__ ch_g,
                                                   float* __restrict__ blob) {
    const int blk = blockIdx.x;
    const int b   = blk >> 7, t = blk & 127;
    const int y0  = (t >> 3) * TILE_H;
    const int x0  = (t & 7) * TILE_W;
    const float* cvb = cv_g + b * CV_PER_B;
    const float* chb = ch_g + b * CH_PER_B;
    float* pv = blob + blk * BLOB_BLK;
    float* ph = pv + CV_SZ;
    for (int i = threadIdx.x; i < CV_SZ; i += 256) {
        int rr = i / CVW, x = i - rr * CVW;
        int gy = y0 - HALO_Y + rr, gx = x0 - HALO_X + x;
        bool ok = (rr >= 1) && (rr <= RH - 1) && (gy >= 1) && (gy <= HH - 1) &&
                  (gx >= 0) && (gx < WW);
        pv[i] = ok ? LAM * cvb[(gy - 1) * WW + gx] : 0.f;
    }
    for (int i = threadIdx.x; i < CH_SZ; i += 256) {
        int rr = i / CHW, xe = i - rr * CHW;
        int gy = y0 - HALO_Y + rr, gxe = x0 - HALO_X + xe;
        bool ok = (xe >= 1) && (xe <= RW - 1) && (gy >= 0) && (gy < HH) &&
                  (gxe >= 1) && (gxe < WW);
        ph[i] = ok ? LAM * chb[gy * (WW - 1) + (gxe - 1)] : 0.f;
    }
}

template <bool ADD_SHIFT, bool SUB_SHIFT>
__global__ __launch_bounds__(NTF, 1) void step_fast(
    const float* __restrict__ src, float* __restrict__ dst,
    const float* __restrict__ blob, const unsigned* __restrict__ key) {
    __shared__ float sb[2][SB_TOT];
    const int blk = blockIdx.x;
    const int b   = blk >> 7, t = blk & 127;
    const int y0  = (t >> 3) * TILE_H;
    const int x0  = (t & 7) * TILE_W;
    const float* srcb = src + b * IMG;
    const float* pv   = blob + blk * BLOB_BLK;
    const float* ph   = pv + CV_SZ;

    float shift = 0.f;
    if (ADD_SHIFT || SUB_SHIFT) shift = (kinv(*key) <= DEPS_) ? DEPS_ : 0.f;
    const int tid = threadIdx.x;

    // ---- unit geometry: 4 wide x 2 tall, rows r0=2*pr, r1=r0+1 ----
    const bool act = tid < NUNIT;
    const int  uc  = act ? tid : 0;
    const int  pr  = uc / NU_ROW;
    const int  px  = uc - pr * NU_ROW;
    const int  x   = px * 4;
    const int  r0  = 2 * pr, r1 = r0 + 1;
    int roff0 = (r0 + 1) * RW + x;
    int roff1 = roff0 + RW;
    if (!act) {                      // trash row: distinct addrs, no races
        roff0 = SSZ + RW + (tid & 3) * 8;
        roff1 = roff0 + 4;
    }

    const int gy0 = y0 - HALO_Y + r0, gy1 = gy0 + 1;
    const int gx  = x0 - HALO_X + x;
    const bool gx_in = (gx >= 0) && (gx <= WW - 4);
    const bool in0 = act && gx_in && (gy0 >= 0) && (gy0 < HH);
    const bool in1 = act && gx_in && (gy1 >= 0) && (gy1 < HH);
    const int goff0 = in0 ? (gy0 * WW + gx) : 0;
    const int goff1 = in1 ? (gy1 * WW + gx) : 0;
    const bool is_int = act && (r0 >= HALO_Y) && (r1 < HALO_Y + TILE_H) &&
                        (x >= HALO_X) && (x < HALO_X + TILE_W);

    // ---- coefficients (baked, predicated; x0-mask for inactive lanes) ----
    const float am = act ? 1.f : 0.f;
    float ca[4], cm[4], cb[4], h0[5], h1[5];
    {
        float4 a = *reinterpret_cast<const float4*>(&pv[r0 * CVW + x]);        // edge above r0
        float4 m = *reinterpret_cast<const float4*>(&pv[r1 * CVW + x]);        // edge r0-r1
        float4 d = *reinterpret_cast<const float4*>(&pv[(r1 + 1) * CVW + x]);  // edge below r1
        ca[0] = a.x * am; ca[1] = a.y * am; ca[2] = a.z * am; ca[3] = a.w * am;
        cm[0] = m.x * am; cm[1] = m.y * am; cm[2] = m.z * am; cm[3] = m.w * am;
        cb[0] = d.x * am; cb[1] = d.y * am; cb[2] = d.z * am; cb[3] = d.w * am;
        float4 u = *reinterpret_cast<const float4*>(&ph[r0 * CHW + x]);
        float  u4 = ph[r0 * CHW + x + 4];
        float4 w = *reinterpret_cast<const float4*>(&ph[r1 * CHW + x]);
        float  w4 = ph[r1 * CHW + x + 4];
        h0[0] = u.x * am; h0[1] = u.y * am; h0[2] = u.z * am; h0[3] = u.w * am; h0[4] = u4 * am;
        h1[0] = w.x * am; h1[1] = w.y * am; h1[2] = w.z * am; h1[3] = w.w * am; h1[4] = w4 * am;
    }

    // ---- initial state ----
    float v0[4] = {0.f, 0.f, 0.f, 0.f}, v1[4] = {0.f, 0.f, 0.f, 0.f};
    if (in0) {
        float4 tv = *reinterpret_cast<const float4*>(srcb + goff0);
        if (ADD_SHIFT) { tv.x += shift; tv.y += shift; tv.z += shift; tv.w += shift; }
        v0[0] = tv.x; v0[1] = tv.y; v0[2] = tv.z; v0[3] = tv.w;
    }
    if (in1) {
        float4 tv = *reinterpret_cast<const float4*>(srcb + goff1);
        if (ADD_SHIFT) { tv.x += shift; tv.y += shift; tv.z += shift; tv.w += shift; }
        v1[0] = tv.x; v1[1] = tv.y; v1[2] = tv.z; v1[3] = tv.w;
    }

    // guard rows (rows 0 and RH+1) zeroed in both buffers
    for (int i = tid; i < RW; i += NTF) {
        sb[0][i] = 0.f; sb[0][(RH + 1) * RW + i] = 0.f;
        sb[1][i] = 0.f; sb[1][(RH + 1) * RW + i] = 0.f;
    }
    *reinterpret_cast<float4*>(&sb[0][roff0]) = float4{v0[0], v0[1], v0[2], v0[3]};
    *reinterpret_cast<float4*>(&sb[0][roff1]) = float4{v1[0], v1[1], v1[2], v1[3]};
    __syncthreads();

    int cur = 0;
    for (int it = 0; it < T_FUSE; ++it) {
        const float* s = sb[cur];
        float4 up = *reinterpret_cast<const float4*>(&s[roff0 - RW]);
        float4 dn = *reinterpret_cast<const float4*>(&s[roff1 + RW]);
        float  lf0 = s[roff0 - 1], rt0 = s[roff0 + 4];
        float  lf1 = s[roff1 - 1], rt1 = s[roff1 + 4];

        float n0[4], n1[4];
        // top row: up from LDS, down-neighbor = v1 (registers)
        n0[0] = v0[0] - ca[0] * (v0[0] - up.x) + cm[0] * (v1[0] - v0[0])
                      - h0[0] * (v0[0] - lf0)  + h0[1] * (v0[1] - v0[0]);
        n0[1] = v0[1] - ca[1] * (v0[1] - up.y) + cm[1] * (v1[1] - v0[1])
                      - h0[1] * (v0[1] - v0[0]) + h0[2] * (v0[2] - v0[1]);
        n0[2] = v0[2] - ca[2] * (v0[2] - up.z) + cm[2] * (v1[2] - v0[2])
                      - h0[2] * (v0[2] - v0[1]) + h0[3] * (v0[3] - v0[2]);
        n0[3] = v0[3] - ca[3] * (v0[3] - up.w) + cm[3] * (v1[3] - v0[3])
                      - h0[3] * (v0[3] - v0[2]) + h0[4] * (rt0 - v0[3]);
        // bottom row: up-neighbor = v0 (registers), down from LDS
        n1[0] = v1[0] - cm[0] * (v1[0] - v0[0]) + cb[0] * (dn.x - v1[0])
                      - h1[0] * (v1[0] - lf1)  + h1[1] * (v1[1] - v1[0]);
        n1[1] = v1[1] - cm[1] * (v1[1] - v0[1]) + cb[1] * (dn.y - v1[1])
                      - h1[1] * (v1[1] - v1[0]) + h1[2] * (v1[2] - v1[1]);
        n1[2] = v1[2] - cm[2] * (v1[2] - v0[2]) + cb[2] * (dn.z - v1[2])
                      - h1[2] * (v1[2] - v1[1]) + h1[3] * (v1[3] - v1[2]);
        n1[3] = v1[3] - cm[3] * (v1[3] - v0[3]) + cb[3] * (dn.w - v1[3])
                      - h1[3] * (v1[3] - v1[2]) + h1[4] * (rt1 - v1[3]);

        int nxt = cur ^ 1;
        *reinterpret_cast<float4*>(&sb[nxt][roff0]) = float4{n0[0], n0[1], n0[2], n0[3]};
        *reinterpret_cast<float4*>(&sb[nxt][roff1]) = float4{n1[0], n1[1], n1[2], n1[3]};
        v0[0] = n0[0]; v0[1] = n0[1]; v0[2] = n0[2]; v0[3] = n0[3];
        v1[0] = n1[0]; v1[1] = n1[1]; v1[2] = n1[2]; v1[3] = n1[3];
        cur = nxt;
        __syncthreads();
    }

    float* dstb = dst + b * IMG;
    if (is_int) {
        float4 o0{v0[0], v0[1], v0[2], v0[3]};
        float4 o1{v1[0], v1[1], v1[2], v1[3]};
        if (SUB_SHIFT) {
            o0.x -= shift; o0.y -= shift; o0.z -= shift; o0.w -= shift;
            o1.x -= shift; o1.y -= shift; o1.z -= shift; o1.w -= shift;
        }
        *reinterpret_cast<float4*>(dstb + goff0) = o0;
        *reinterpret_cast<float4*>(dstb + goff1) = o1;
    }
}

// -------- fallback (round-2 verified, inline gather, 256 threads) --------
template <bool ADD_SHIFT, bool SUB_SHIFT>
__global__ __launch_bounds__(256, 1) void step_fused(
    const float* __restrict__ src, float* __restrict__ dst,
    const float* __restrict__ cv_g, const float* __restrict__ ch_g,
    const unsigned* __restrict__ key) {
    __shared__ float sb[2][SSZ];
    const int blk = blockIdx.x;
    const int b = blk >> 7, t = blk & 127;
    const int y0 = (t >> 3) * TILE_H, x0 = (t & 7) * TILE_W;
    const float* cvb = cv_g + b * CV_PER_B;
    const float* chb = ch_g + b * CH_PER_B;
    const float* srcb = src + b * IMG;
    float* dstb = dst + b * IMG;
    float shift = 0.f;
    if (ADD_SHIFT || SUB_SHIFT) shift = (kinv(*key) <= DEPS_) ? DEPS_ : 0.f;
    const int tid = threadIdx.x;
    float v[QPT_F][4], cu[QPT_F][4], cd[QPT_F][4], chq[QPT_F][5];
    int roff[QPT_F], rr[QPT_F], xx[QPT_F];
    bool act[QPT_F];
#pragma unroll
    for (int q = 0; q < QPT_F; ++q) {
        int qi = tid + q * 256;
        act[q] = qi < NQUAD;
        int qc = act[q] ? qi : 0;
        int r = qc / NQ_ROW;
        int x = (qc - r * NQ_ROW) * 4;
        rr[q] = r; xx[q] = x;
        roff[q] = (r + 1) * RW + x;
        int gy = y0 - HALO_Y + r, gx = x0 - HALO_X + x;
        bool gy_in = (gy >= 0) && (gy < HH);
#pragma unroll
        for (int j = 0; j < 4; ++j) {
            int gxx = gx + j;
            bool gx_in = (gxx >= 0) && (gxx < WW);
            bool vin = act[q] && gy_in && gx_in;
            float val = vin ? srcb[gy * WW + gxx] : 0.f;
            if (ADD_SHIFT) val += shift;
            v[q][j] = vin ? val : 0.f;
            bool up_ok = act[q] && (r >= 1) && (gy >= 1) && (gy < HH) && gx_in;
            cu[q][j] = up_ok ? LAM * cvb[(gy - 1) * WW + gxx] : 0.f;
            bool dn_ok = act[q] && (r <= RH - 2) && (gy >= 0) && (gy < HH - 1) && gx_in;
            cd[q][j] = dn_ok ? LAM * cvb[gy * WW + gxx] : 0.f;
        }
#pragma unroll
        for (int jj = 0; jj < 5; ++jj) {
            int xe = x + jj, gxe = gx + jj;
            bool ok = act[q] && (xe >= 1) && (xe <= RW - 1) && gy_in &&
                      (gxe >= 1) && (gxe < WW);
            chq[q][jj] = ok ? LAM * chb[gy * (WW - 1) + (gxe - 1)] : 0.f;
        }
    }
    for (int i = tid; i < RW; i += 256) {
        sb[0][i] = 0.f; sb[0][(RH + 1) * RW + i] = 0.f;
        sb[1][i] = 0.f; sb[1][(RH + 1) * RW + i] = 0.f;
    }
#pragma unroll
    for (int q = 0; q < QPT_F; ++q)
        if (act[q])
            *reinterpret_cast<float4*>(&sb[0][roff[q]]) =
                float4{v[q][0], v[q][1], v[q][2], v[q][3]};
    __syncthreads();
    int cur = 0;
    for (int it = 0; it < T_FUSE; ++it) {
        float nv[QPT_F][4];
#pragma unroll
        for (int q = 0; q < QPT_F; ++q) {
            const float* s = sb[cur];
            float4 up = *reinterpret_cast<const float4*>(&s[roff[q] - RW]);
            float4 dn = *reinterpret_cast<const float4*>(&s[roff[q] + RW]);
            float lf = s[roff[q] - 1];
            float rt = s[roff[q] + 4];
            float c0 = v[q][0], c1 = v[q][1], c2 = v[q][2], c3 = v[q][3];
            nv[q][0] = c0 - cu[q][0] * (c0 - up.x) + cd[q][0] * (dn.x - c0)
                          - chq[q][0] * (c0 - lf) + chq[q][1] * (c1 - c0);
            nv[q][1] = c1 - cu[q][1] * (c1 - up.y) + cd[q][1] * (dn.y - c1)
                          - chq[q][1] * (c1 - c0) + chq[q][2] * (c2 - c1);
            nv[q][2] = c2 - cu[q][2] * (c2 - up.z) + cd[q][2] * (dn.z - c2)
                          - chq[q][2] * (c2 - c1) + chq[q][3] * (c3 - c2);
            nv[q][3] = c3 - cu[q][3] * (c3 - up.w) + cd[q][3] * (dn.w - c3)
                          - chq[q][3] * (c3 - c2) + chq[q][4] * (rt - c3);
        }
        int nxt = cur ^ 1;
#pragma unroll
        for (int q = 0; q < QPT_F; ++q) {
            if (act[q])
                *reinterpret_cast<float4*>(&sb[nxt][roff[q]]) =
                    float4{nv[q][0], nv[q][1], nv[q][2], nv[q][3]};
            v[q][0] = nv[q][0]; v[q][1] = nv[q][1];
            v[q][2] = nv[q][2]; v[q][3] = nv[q][3];
        }
        cur = nxt;
        __syncthreads();
    }
#pragma unroll
    for (int q = 0; q < QPT_F; ++q) {
        if (!act[q]) continue;
        int r = rr[q], x = xx[q];
        if (r >= HALO_Y && r < HALO_Y + TILE_H && x >= HALO_X && x < HALO_X + TILE_W) {
            int gy = y0 - HALO_Y + r, gx = x0 - HALO_X + x;
            float4 o{v[q][0], v[q][1], v[q][2], v[q][3]};
            if (SUB_SHIFT) { o.x -= shift; o.y -= shift; o.z -= shift; o.w -= shift; }
            *reinterpret_cast<float4*>(dstb + gy * WW + gx) = o;
        }
    }
}

extern "C" void kernel_launch(void* const* d_in, const int* in_sizes, int n_in,
                              void* d_out, int out_size, void* d_ws, size_t ws_size,
                              hipStream_t stream) {
    const float* guide   = (const float*)d_in[0];
    const float* initial = (const float*)d_in[1];
    float* out    = (float*)d_out;
    float* out_y  = out;
    float* out_cv = out + N_DEPTH;
    float* out_ch = out + N_DEPTH + N_CV;

    unsigned* key = (unsigned*)d_ws;
    float* wsf    = (float*)d_ws;
    float* bufA   = wsf + 64;
    float* bufB   = bufA + N_DEPTH;
    float* blob   = bufB + N_DEPTH;

    const size_t need = (size_t)(64 + 2 * N_DEPTH + 256 * BLOB_BLK) * 4;
    const bool fast = ws_size >= need;

    hipLaunchKernelGGL(init_key_kernel, dim3(1), dim3(1), 0, stream, key);
    hipLaunchKernelGGL(min_kernel, dim3(256), dim3(256), 0, stream, initial, key);

    int nco = N_CV + N_CH;
    hipLaunchKernelGGL(coeff_kernel, dim3((nco + 255) / 256), dim3(256), 0, stream,
                       guide, out_cv, out_ch);
    if (fast)
        hipLaunchKernelGGL(prep_planes, dim3(256), dim3(256), 0, stream,
                           out_cv, out_ch, blob);

    float* bufs[2] = {bufA, bufB};
    for (int k = 0; k < NSS; ++k) {
        const float* src = (k == 0) ? initial : bufs[(k + 1) & 1];
        float*       dst = (k == NSS - 1) ? out_y : bufs[k & 1];
        if (fast) {
            if (k == 0)
                hipLaunchKernelGGL((step_fast<true, false>), dim3(256), dim3(NTF), 0,
                                   stream, src, dst, blob, key);
            else if (k == NSS - 1)
                hipLaunchKernelGGL((step_fast<false, true>), dim3(256), dim3(NTF), 0,
                                   stream, src, dst, blob, key);
            else
                hipLaunchKernelGGL((step_fast<false, false>), dim3(256), dim3(NTF), 0,
                                   stream, src, dst, blob, key);
        } else {
            if (k == 0)
                hipLaunchKernelGGL((step_fused<true, false>), dim3(256), dim3(256), 0,
                                   stream, src, dst, out_cv, out_ch, key);
            else if (k == NSS - 1)
                hipLaunchKernelGGL((step_fused<false, true>), dim3(256), dim3(256), 0,
                                   stream, src, dst, out_cv, out_ch, key);
            else
                hipLaunchKernelGGL((step_fused<false, false>), dim3(256), dim3(256), 0,
                                   stream, src, dst, out_cv, out_ch, key);
        }
    }
}

// Round 3
// 494.816 us; speedup vs baseline: 1.1364x; 1.0072x over previous
//
#include <hip/hip_runtime.h>

// Perona-Malik diffusion, 500 iters = 50 launches x 10 LDS-fused steps.
// Round-7 change vs round 6: kill the measured 1.17M/dispatch LDS bank
// conflicts. The lf/rt scalar reads had a 16B lane stride with fixed
// addr%4 -> all 64 lanes hit the 8 banks sharing low-2 bank bits
// (8 words/bank vs 2 min). Horizontal edges now go through a dense
// per-unit edge array: write edge4[u+1]={v0[0],v1[0],v0[3],v1[3]} (b128,
// uniform 8/bank), read neighbors via two b64s at consecutive-unit
// addresses (uniform 4/bank = wave64 minimum). Row stride padded 88->92:
// makes up/dn/write b128s exactly uniform 8/bank too. Same values, same
// FMA order -> bit-identical. All boundary/inactive reads are finite and
// multiplied by baked-zero coefficients.

#define HH 512
#define WW 512
#define NB 2
static constexpr float LAM   = 0.24f;
static constexpr float KCOND = 0.03f;
static constexpr float DEPS_ = 0.1f;
static constexpr int IMG      = HH * WW;
static constexpr int N_DEPTH  = NB * IMG;
static constexpr int CV_PER_B = (HH - 1) * WW;
static constexpr int CH_PER_B = HH * (WW - 1);
static constexpr int N_CV     = NB * CV_PER_B;
static constexpr int N_CH     = NB * CH_PER_B;

static constexpr int T_FUSE = 10, NSS = 50;       // 50 x 10 = 500
static constexpr int TILE_W = 64, TILE_H = 32;
static constexpr int HALO_X = 12, HALO_Y = 10;
static constexpr int RW = TILE_W + 2 * HALO_X;    // 88
static constexpr int RH = TILE_H + 2 * HALO_Y;    // 52
static constexpr int NQ_ROW = RW / 4;             // 22
static constexpr int NQUAD  = NQ_ROW * RH;        // 1144
static constexpr int SSZ    = (RH + 2) * RW;      // fallback layout (4752)

// fast path: 4x2 units, one per thread
static constexpr int NU_ROW = RW / 4;              // 22 units per row-pair
static constexpr int NU_COL = RH / 2;              // 26 row-pairs
static constexpr int NUNIT  = NU_ROW * NU_COL;     // 572
static constexpr int NTF    = 576;                 // 9 waves

// fast-path LDS layout (floats), per ping-pong buffer:
//   rows   : (RH+2) x S_LDS  (stride 92 -> uniform b128 banks)
//   trash  : S_LDS           (inactive-lane row writes)
//   edge4  : EDGE_ENT float4 (per-unit {v0[0],v1[0],v0[3],v1[3]}, +1 offset)
static constexpr int S_LDS    = 92;
static constexpr int ROWS_SZ  = (RH + 2) * S_LDS;       // 4968
static constexpr int TRASH_OFF = ROWS_SZ;               // 4968
static constexpr int EDGE_OFF = ROWS_SZ + S_LDS;        // 5060 (16B aligned)
static constexpr int EDGE_ENT = 580;                    // entries 0..577 used
static constexpr int BUF_SZ   = EDGE_OFF + EDGE_ENT * 4; // 7380

// coefficient planes (per block): CV rows 0..RH (edge above region row r),
// CH row width padded to 96 so the 5-edge read is aligned f4 + scalar.
static constexpr int CVW = RW;                     // 88
static constexpr int CV_SZ = (RH + 1) * CVW;       // 4664
static constexpr int CHW = RW + 8;                 // 96
static constexpr int CH_SZ = RH * CHW;             // 4992
static constexpr int BLOB_BLK = CV_SZ + CH_SZ;     // 9656 floats/block

// fallback path (round-2 verified): 256 threads, 5 quads/thread
static constexpr int QPT_F = 5;

// ---- monotone float<->uint key for atomic min ----
__device__ __forceinline__ unsigned fkey(float f) {
    unsigned u = __float_as_uint(f);
    return (u & 0x80000000u) ? ~u : (u | 0x80000000u);
}
__device__ __forceinline__ float kinv(unsigned k) {
    return __uint_as_float((k & 0x80000000u) ? (k & 0x7fffffffu) : ~k);
}

__global__ void init_key_kernel(unsigned* key) { *key = 0xFFFFFFFFu; }

__global__ void min_kernel(const float* __restrict__ x, unsigned* key) {
    float m = 3.4e38f;
    for (int idx = blockIdx.x * blockDim.x + threadIdx.x; idx < N_DEPTH;
         idx += gridDim.x * blockDim.x)
        m = fminf(m, x[idx]);
    for (int off = 32; off > 0; off >>= 1) m = fminf(m, __shfl_down(m, off, 64));
    __shared__ float sm[4];
    int lane = threadIdx.x & 63, wv = threadIdx.x >> 6;
    if (lane == 0) sm[wv] = m;
    __syncthreads();
    if (threadIdx.x == 0) {
        float mm = fminf(fminf(sm[0], sm[1]), fminf(sm[2], sm[3]));
        atomicMin(key, fkey(mm));
    }
}

__global__ void coeff_kernel(const float* __restrict__ g, float* __restrict__ cv,
                             float* __restrict__ chh) {
    int idx = blockIdx.x * blockDim.x + threadIdx.x;
    constexpr float kk = KCOND * KCOND;
    if (idx < N_CV) {
        int b = idx / CV_PER_B;
        int r = idx - b * CV_PER_B;
        int i = r >> 9, j = r & (WW - 1);
        const float* gb = g + b * 3 * IMG + i * WW + j;
        float s = 0.f;
#pragma unroll
        for (int c = 0; c < 3; ++c) s += fabsf(gb[c * IMG + WW] - gb[c * IMG]);
        float m = s / 3.0f;
        cv[idx] = 1.0f / (1.0f + (m * m) / kk);
    } else if (idx < N_CV + N_CH) {
        int t = idx - N_CV;
        int b = t / CH_PER_B;
        int r = t - b * CH_PER_B;
        int i = r / (WW - 1);
        int j = r - i * (WW - 1);
        const float* gb = g + b * 3 * IMG + i * WW + j;
        float s = 0.f;
#pragma unroll
        for (int c = 0; c < 3; ++c) s += fabsf(gb[c * IMG + 1] - gb[c * IMG]);
        float m = s / 3.0f;
        chh[t] = 1.0f / (1.0f + (m * m) / kk);
    }
}

// One-time: bake predicated L*cv / L*ch into dense per-block planes.
// CV[rr][x] = coeff of vertical edge ABOVE region row rr (0 where invalid):
//   cu(region row r) = CV[r], cd(region row r) = CV[r+1].
// CH[rr][xe] = coeff of horizontal edge whose RIGHT pixel is region col xe.
__global__ __launch_bounds__(256) void prep_planes(const float* __restrict__ cv_g,
                                                   const float* __restrict__ ch_g,
                                                   float* __restrict__ blob) {
    const int blk = blockIdx.x;
    const int b   = blk >> 7, t = blk & 127;
    const int y0  = (t >> 3) * TILE_H;
    const int x0  = (t & 7) * TILE_W;
    const float* cvb = cv_g + b * CV_PER_B;
    const float* chb = ch_g + b * CH_PER_B;
    float* pv = blob + blk * BLOB_BLK;
    float* ph = pv + CV_SZ;
    for (int i = threadIdx.x; i < CV_SZ; i += 256) {
        int rr = i / CVW, x = i - rr * CVW;
        int gy = y0 - HALO_Y + rr, gx = x0 - HALO_X + x;
        bool ok = (rr >= 1) && (rr <= RH - 1) && (gy >= 1) && (gy <= HH - 1) &&
                  (gx >= 0) && (gx < WW);
        pv[i] = ok ? LAM * cvb[(gy - 1) * WW + gx] : 0.f;
    }
    for (int i = threadIdx.x; i < CH_SZ; i += 256) {
        int rr = i / CHW, xe = i - rr * CHW;
        int gy = y0 - HALO_Y + rr, gxe = x0 - HALO_X + xe;
        bool ok = (xe >= 1) && (xe <= RW - 1) && (gy >= 0) && (gy < HH) &&
                  (gxe >= 1) && (gxe < WW);
        ph[i] = ok ? LAM * chb[gy * (WW - 1) + (gxe - 1)] : 0.f;
    }
}

template <bool ADD_SHIFT, bool SUB_SHIFT>
__global__ __launch_bounds__(NTF, 1) void step_fast(
    const float* __restrict__ src, float* __restrict__ dst,
    const float* __restrict__ blob, const unsigned* __restrict__ key) {
    __shared__ float sb[2][BUF_SZ];
    const int blk = blockIdx.x;
    const int b   = blk >> 7, t = blk & 127;
    const int y0  = (t >> 3) * TILE_H;
    const int x0  = (t & 7) * TILE_W;
    const float* srcb = src + b * IMG;
    const float* pv   = blob + blk * BLOB_BLK;
    const float* ph   = pv + CV_SZ;

    float shift = 0.f;
    if (ADD_SHIFT || SUB_SHIFT) shift = (kinv(*key) <= DEPS_) ? DEPS_ : 0.f;
    const int tid = threadIdx.x;

    // ---- unit geometry: 4 wide x 2 tall, rows r0=2*pr, r1=r0+1 ----
    const bool act = tid < NUNIT;
    const int  uc  = act ? tid : 0;
    const int  pr  = uc / NU_ROW;
    const int  px  = uc - pr * NU_ROW;
    const int  x   = px * 4;
    const int  r0  = 2 * pr, r1 = r0 + 1;
    int roff0 = (r0 + 1) * S_LDS + x;
    int roff1 = roff0 + S_LDS;
    if (!act) {                      // trash area: distinct addrs, no races
        roff0 = TRASH_OFF + (tid & 3) * 8;
        roff1 = roff0 + 4;
    }
    // edge array offsets (entries shifted by +1 so u=0 reads entry 0)
    const int e_w  = EDGE_OFF + (tid + 1) * 4;   // own write
    const int e_lf = EDGE_OFF + tid * 4 + 2;     // left nbr's {v0[3],v1[3]}
    const int e_rt = EDGE_OFF + (tid + 2) * 4;   // right nbr's {v0[0],v1[0]}

    const int gy0 = y0 - HALO_Y + r0, gy1 = gy0 + 1;
    const int gx  = x0 - HALO_X + x;
    const bool gx_in = (gx >= 0) && (gx <= WW - 4);
    const bool in0 = act && gx_in && (gy0 >= 0) && (gy0 < HH);
    const bool in1 = act && gx_in && (gy1 >= 0) && (gy1 < HH);
    const int goff0 = in0 ? (gy0 * WW + gx) : 0;
    const int goff1 = in1 ? (gy1 * WW + gx) : 0;
    const bool is_int = act && (r0 >= HALO_Y) && (r1 < HALO_Y + TILE_H) &&
                        (x >= HALO_X) && (x < HALO_X + TILE_W);

    // ---- coefficients (baked, predicated; x0-mask for inactive lanes) ----
    const float am = act ? 1.f : 0.f;
    float ca[4], cm[4], cb[4], h0[5], h1[5];
    {
        float4 a = *reinterpret_cast<const float4*>(&pv[r0 * CVW + x]);        // edge above r0
        float4 m = *reinterpret_cast<const float4*>(&pv[r1 * CVW + x]);        // edge r0-r1
        float4 d = *reinterpret_cast<const float4*>(&pv[(r1 + 1) * CVW + x]);  // edge below r1
        ca[0] = a.x * am; ca[1] = a.y * am; ca[2] = a.z * am; ca[3] = a.w * am;
        cm[0] = m.x * am; cm[1] = m.y * am; cm[2] = m.z * am; cm[3] = m.w * am;
        cb[0] = d.x * am; cb[1] = d.y * am; cb[2] = d.z * am; cb[3] = d.w * am;
        float4 u = *reinterpret_cast<const float4*>(&ph[r0 * CHW + x]);
        float  u4 = ph[r0 * CHW + x + 4];
        float4 w = *reinterpret_cast<const float4*>(&ph[r1 * CHW + x]);
        float  w4 = ph[r1 * CHW + x + 4];
        h0[0] = u.x * am; h0[1] = u.y * am; h0[2] = u.z * am; h0[3] = u.w * am; h0[4] = u4 * am;
        h1[0] = w.x * am; h1[1] = w.y * am; h1[2] = w.z * am; h1[3] = w.w * am; h1[4] = w4 * am;
    }

    // ---- initial state ----
    float v0[4] = {0.f, 0.f, 0.f, 0.f}, v1[4] = {0.f, 0.f, 0.f, 0.f};
    if (in0) {
        float4 tv = *reinterpret_cast<const float4*>(srcb + goff0);
        if (ADD_SHIFT) { tv.x += shift; tv.y += shift; tv.z += shift; tv.w += shift; }
        v0[0] = tv.x; v0[1] = tv.y; v0[2] = tv.z; v0[3] = tv.w;
    }
    if (in1) {
        float4 tv = *reinterpret_cast<const float4*>(srcb + goff1);
        if (ADD_SHIFT) { tv.x += shift; tv.y += shift; tv.z += shift; tv.w += shift; }
        v1[0] = tv.x; v1[1] = tv.y; v1[2] = tv.z; v1[3] = tv.w;
    }

    // guard rows (rows 0 and RH+1) zeroed in both buffers
    for (int i = tid; i < S_LDS; i += NTF) {
        sb[0][i] = 0.f; sb[0][(RH + 1) * S_LDS + i] = 0.f;
        sb[1][i] = 0.f; sb[1][(RH + 1) * S_LDS + i] = 0.f;
    }
    if (tid == 0) {
        float4 z{0.f, 0.f, 0.f, 0.f};
        *reinterpret_cast<float4*>(&sb[0][EDGE_OFF]) = z;            // entry 0
        *reinterpret_cast<float4*>(&sb[1][EDGE_OFF]) = z;
        *reinterpret_cast<float4*>(&sb[0][EDGE_OFF + 577 * 4]) = z;  // entry 577
        *reinterpret_cast<float4*>(&sb[1][EDGE_OFF + 577 * 4]) = z;
    }
    *reinterpret_cast<float4*>(&sb[0][roff0]) = float4{v0[0], v0[1], v0[2], v0[3]};
    *reinterpret_cast<float4*>(&sb[0][roff1]) = float4{v1[0], v1[1], v1[2], v1[3]};
    *reinterpret_cast<float4*>(&sb[0][e_w])   = float4{v0[0], v1[0], v0[3], v1[3]};
    __syncthreads();

    int cur = 0;
    for (int it = 0; it < T_FUSE; ++it) {
        const float* s = sb[cur];
        float2 lfp = *reinterpret_cast<const float2*>(&s[e_lf]);  // {lf0, lf1}
        float2 rtp = *reinterpret_cast<const float2*>(&s[e_rt]);  // {rt0, rt1}
        float4 up = *reinterpret_cast<const float4*>(&s[roff0 - S_LDS]);
        float4 dn = *reinterpret_cast<const float4*>(&s[roff1 + S_LDS]);

        float n0[4], n1[4];
        // top row: up from LDS, down-neighbor = v1 (registers)
        n0[0] = v0[0] - ca[0] * (v0[0] - up.x) + cm[0] * (v1[0] - v0[0])
                      - h0[0] * (v0[0] - lfp.x) + h0[1] * (v0[1] - v0[0]);
        n0[1] = v0[1] - ca[1] * (v0[1] - up.y) + cm[1] * (v1[1] - v0[1])
                      - h0[1] * (v0[1] - v0[0]) + h0[2] * (v0[2] - v0[1]);
        n0[2] = v0[2] - ca[2] * (v0[2] - up.z) + cm[2] * (v1[2] - v0[2])
                      - h0[2] * (v0[2] - v0[1]) + h0[3] * (v0[3] - v0[2]);
        n0[3] = v0[3] - ca[3] * (v0[3] - up.w) + cm[3] * (v1[3] - v0[3])
                      - h0[3] * (v0[3] - v0[2]) + h0[4] * (rtp.x - v0[3]);
        // bottom row: up-neighbor = v0 (registers), down from LDS
        n1[0] = v1[0] - cm[0] * (v1[0] - v0[0]) + cb[0] * (dn.x - v1[0])
                      - h1[0] * (v1[0] - lfp.y) + h1[1] * (v1[1] - v1[0]);
        n1[1] = v1[1] - cm[1] * (v1[1] - v0[1]) + cb[1] * (dn.y - v1[1])
                      - h1[1] * (v1[1] - v1[0]) + h1[2] * (v1[2] - v1[1]);
        n1[2] = v1[2] - cm[2] * (v1[2] - v0[2]) + cb[2] * (dn.z - v1[2])
                      - h1[2] * (v1[2] - v1[1]) + h1[3] * (v1[3] - v1[2]);
        n1[3] = v1[3] - cm[3] * (v1[3] - v0[3]) + cb[3] * (dn.w - v1[3])
                      - h1[3] * (v1[3] - v1[2]) + h1[4] * (rtp.y - v1[3]);

        int nxt = cur ^ 1;
        float* d = sb[nxt];
        *reinterpret_cast<float4*>(&d[roff0]) = float4{n0[0], n0[1], n0[2], n0[3]};
        *reinterpret_cast<float4*>(&d[roff1]) = float4{n1[0], n1[1], n1[2], n1[3]};
        *reinterpret_cast<float4*>(&d[e_w])   = float4{n0[0], n1[0], n0[3], n1[3]};
        v0[0] = n0[0]; v0[1] = n0[1]; v0[2] = n0[2]; v0[3] = n0[3];
        v1[0] = n1[0]; v1[1] = n1[1]; v1[2] = n1[2]; v1[3] = n1[3];
        cur = nxt;
        __syncthreads();
    }

    float* dstb = dst + b * IMG;
    if (is_int) {
        float4 o0{v0[0], v0[1], v0[2], v0[3]};
        float4 o1{v1[0], v1[1], v1[2], v1[3]};
        if (SUB_SHIFT) {
            o0.x -= shift; o0.y -= shift; o0.z -= shift; o0.w -= shift;
            o1.x -= shift; o1.y -= shift; o1.z -= shift; o1.w -= shift;
        }
        *reinterpret_cast<float4*>(dstb + goff0) = o0;
        *reinterpret_cast<float4*>(dstb + goff1) = o1;
    }
}

// -------- fallback (round-2 verified, inline gather, 256 threads) --------
template <bool ADD_SHIFT, bool SUB_SHIFT>
__global__ __launch_bounds__(256, 1) void step_fused(
    const float* __restrict__ src, float* __restrict__ dst,
    const float* __restrict__ cv_g, const float* __restrict__ ch_g,
    const unsigned* __restrict__ key) {
    __shared__ float sb[2][SSZ];
    const int blk = blockIdx.x;
    const int b = blk >> 7, t = blk & 127;
    const int y0 = (t >> 3) * TILE_H, x0 = (t & 7) * TILE_W;
    const float* cvb = cv_g + b * CV_PER_B;
    const float* chb = ch_g + b * CH_PER_B;
    const float* srcb = src + b * IMG;
    float* dstb = dst + b * IMG;
    float shift = 0.f;
    if (ADD_SHIFT || SUB_SHIFT) shift = (kinv(*key) <= DEPS_) ? DEPS_ : 0.f;
    const int tid = threadIdx.x;
    float v[QPT_F][4], cu[QPT_F][4], cd[QPT_F][4], chq[QPT_F][5];
    int roff[QPT_F], rr[QPT_F], xx[QPT_F];
    bool act[QPT_F];
#pragma unroll
    for (int q = 0; q < QPT_F; ++q) {
        int qi = tid + q * 256;
        act[q] = qi < NQUAD;
        int qc = act[q] ? qi : 0;
        int r = qc / NQ_ROW;
        int x = (qc - r * NQ_ROW) * 4;
        rr[q] = r; xx[q] = x;
        roff[q] = (r + 1) * RW + x;
        int gy = y0 - HALO_Y + r, gx = x0 - HALO_X + x;
        bool gy_in = (gy >= 0) && (gy < HH);
#pragma unroll
        for (int j = 0; j < 4; ++j) {
            int gxx = gx + j;
            bool gx_in = (gxx >= 0) && (gxx < WW);
            bool vin = act[q] && gy_in && gx_in;
            float val = vin ? srcb[gy * WW + gxx] : 0.f;
            if (ADD_SHIFT) val += shift;
            v[q][j] = vin ? val : 0.f;
            bool up_ok = act[q] && (r >= 1) && (gy >= 1) && (gy < HH) && gx_in;
            cu[q][j] = up_ok ? LAM * cvb[(gy - 1) * WW + gxx] : 0.f;
            bool dn_ok = act[q] && (r <= RH - 2) && (gy >= 0) && (gy < HH - 1) && gx_in;
            cd[q][j] = dn_ok ? LAM * cvb[gy * WW + gxx] : 0.f;
        }
#pragma unroll
        for (int jj = 0; jj < 5; ++jj) {
            int xe = x + jj, gxe = gx + jj;
            bool ok = act[q] && (xe >= 1) && (xe <= RW - 1) && gy_in &&
                      (gxe >= 1) && (gxe < WW);
            chq[q][jj] = ok ? LAM * chb[gy * (WW - 1) + (gxe - 1)] : 0.f;
        }
    }
    for (int i = tid; i < RW; i += 256) {
        sb[0][i] = 0.f; sb[0][(RH + 1) * RW + i] = 0.f;
        sb[1][i] = 0.f; sb[1][(RH + 1) * RW + i] = 0.f;
    }
#pragma unroll
    for (int q = 0; q < QPT_F; ++q)
        if (act[q])
            *reinterpret_cast<float4*>(&sb[0][roff[q]]) =
                float4{v[q][0], v[q][1], v[q][2], v[q][3]};
    __syncthreads();
    int cur = 0;
    for (int it = 0; it < T_FUSE; ++it) {
        float nv[QPT_F][4];
#pragma unroll
        for (int q = 0; q < QPT_F; ++q) {
            const float* s = sb[cur];
            float4 up = *reinterpret_cast<const float4*>(&s[roff[q] - RW]);
            float4 dn = *reinterpret_cast<const float4*>(&s[roff[q] + RW]);
            float lf = s[roff[q] - 1];
            float rt = s[roff[q] + 4];
            float c0 = v[q][0], c1 = v[q][1], c2 = v[q][2], c3 = v[q][3];
            nv[q][0] = c0 - cu[q][0] * (c0 - up.x) + cd[q][0] * (dn.x - c0)
                          - chq[q][0] * (c0 - lf) + chq[q][1] * (c1 - c0);
            nv[q][1] = c1 - cu[q][1] * (c1 - up.y) + cd[q][1] * (dn.y - c1)
                          - chq[q][1] * (c1 - c0) + chq[q][2] * (c2 - c1);
            nv[q][2] = c2 - cu[q][2] * (c2 - up.z) + cd[q][2] * (dn.z - c2)
                          - chq[q][2] * (c2 - c1) + chq[q][3] * (c3 - c2);
            nv[q][3] = c3 - cu[q][3] * (c3 - up.w) + cd[q][3] * (dn.w - c3)
                          - chq[q][3] * (c3 - c2) + chq[q][4] * (rt - c3);
        }
        int nxt = cur ^ 1;
#pragma unroll
        for (int q = 0; q < QPT_F; ++q) {
            if (act[q])
                *reinterpret_cast<float4*>(&sb[nxt][roff[q]]) =
                    float4{nv[q][0], nv[q][1], nv[q][2], nv[q][3]};
            v[q][0] = nv[q][0]; v[q][1] = nv[q][1];
            v[q][2] = nv[q][2]; v[q][3] = nv[q][3];
        }
        cur = nxt;
        __syncthreads();
    }
#pragma unroll
    for (int q = 0; q < QPT_F; ++q) {
        if (!act[q]) continue;
        int r = rr[q], x = xx[q];
        if (r >= HALO_Y && r < HALO_Y + TILE_H && x >= HALO_X && x < HALO_X + TILE_W) {
            int gy = y0 - HALO_Y + r, gx = x0 - HALO_X + x;
            float4 o{v[q][0], v[q][1], v[q][2], v[q][3]};
            if (SUB_SHIFT) { o.x -= shift; o.y -= shift; o.z -= shift; o.w -= shift; }
            *reinterpret_cast<float4*>(dstb + gy * WW + gx) = o;
        }
    }
}

extern "C" void kernel_launch(void* const* d_in, const int* in_sizes, int n_in,
                              void* d_out, int out_size, void* d_ws, size_t ws_size,
                              hipStream_t stream) {
    const float* guide   = (const float*)d_in[0];
    const float* initial = (const float*)d_in[1];
    float* out    = (float*)d_out;
    float* out_y  = out;
    float* out_cv = out + N_DEPTH;
    float* out_ch = out + N_DEPTH + N_CV;

    unsigned* key = (unsigned*)d_ws;
    float* wsf    = (float*)d_ws;
    float* bufA   = wsf + 64;
    float* bufB   = bufA + N_DEPTH;
    float* blob   = bufB + N_DEPTH;

    const size_t need = (size_t)(64 + 2 * N_DEPTH + 256 * BLOB_BLK) * 4;
    const bool fast = ws_size >= need;

    hipLaunchKernelGGL(init_key_kernel, dim3(1), dim3(1), 0, stream, key);
    hipLaunchKernelGGL(min_kernel, dim3(256), dim3(256), 0, stream, initial, key);

    int nco = N_CV + N_CH;
    hipLaunchKernelGGL(coeff_kernel, dim3((nco + 255) / 256), dim3(256), 0, stream,
                       guide, out_cv, out_ch);
    if (fast)
        hipLaunchKernelGGL(prep_planes, dim3(256), dim3(256), 0, stream,
                           out_cv, out_ch, blob);

    float* bufs[2] = {bufA, bufB};
    for (int k = 0; k < NSS; ++k) {
        const float* src = (k == 0) ? initial : bufs[(k + 1) & 1];
        float*       dst = (k == NSS - 1) ? out_y : bufs[k & 1];
        if (fast) {
            if (k == 0)
                hipLaunchKernelGGL((step_fast<true, false>), dim3(256), dim3(NTF), 0,
                                   stream, src, dst, blob, key);
            else if (k == NSS - 1)
                hipLaunchKernelGGL((step_fast<false, true>), dim3(256), dim3(NTF), 0,
                                   stream, src, dst, blob, key);
            else
                hipLaunchKernelGGL((step_fast<false, false>), dim3(256), dim3(NTF), 0,
                                   stream, src, dst, blob, key);
        } else {
            if (k == 0)
                hipLaunchKernelGGL((step_fused<true, false>), dim3(256), dim3(256), 0,
                                   stream, src, dst, out_cv, out_ch, key);
            else if (k == NSS - 1)
                hipLaunchKernelGGL((step_fused<false, true>), dim3(256), dim3(256), 0,
                                   stream, src, dst, out_cv, out_ch, key);
            else
                hipLaunchKernelGGL((step_fused<false, false>), dim3(256), dim3(256), 0,
                                   stream, src, dst, out_cv, out_ch, key);
        }
    }
}